// Round 4
// baseline (785.806 us; speedup 1.0000x reference)
//
#include <hip/hip_runtime.h>

typedef __attribute__((ext_vector_type(8))) short  short8;
typedef __attribute__((ext_vector_type(4))) float  f32x4;

#define MFMA16(A,B,C) __builtin_amdgcn_mfma_f32_16x16x32_bf16((A),(B),(C),0,0,0)

// split fp32 into bf16 hi + bf16 lo (x ~= hi + lo, residual < 2^-17 |x|)
__device__ __forceinline__ void splitf(float x, unsigned short &h, unsigned short &l) {
    unsigned u  = __float_as_uint(x);
    unsigned hu = (u + 0x8000u) & 0xFFFF0000u;
    h = (unsigned short)(hu >> 16);
    float r = x - __uint_as_float(hu);
    l = (unsigned short)((__float_as_uint(r) + 0x8000u) >> 16);
}

__device__ __forceinline__ void split8(const f32x4 a, const f32x4 b, short8 &h, short8 &l) {
#pragma unroll
    for (int i = 0; i < 4; ++i) {
        unsigned short hh, ll;
        splitf(a[i], hh, ll); h[i] = (short)hh; l[i] = (short)ll;
    }
#pragma unroll
    for (int i = 0; i < 4; ++i) {
        unsigned short hh, ll;
        splitf(b[i], hh, ll); h[4 + i] = (short)hh; l[4 + i] = (short)ll;
    }
}

// XOR-swizzled byte offset inside a [16 rows][64 bf16] plane (row stride 128B).
__device__ __forceinline__ unsigned swz(unsigned row, unsigned colbyte) {
    return row * 128u + (colbyte ^ ((row & 7u) << 4));
}

// barrier that does NOT drain vmcnt: LDS visibility only. Prefetched global
// loads stay in flight across it (the whole point of the R4 pipeline).
__device__ __forceinline__ void barrier_nv() {
    __builtin_amdgcn_sched_barrier(0);
    asm volatile("s_waitcnt lgkmcnt(0)" ::: "memory");
    __builtin_amdgcn_s_barrier();
    __builtin_amdgcn_sched_barrier(0);
}

// One tree level. Block = 4 waves; wave w owns output cols [16w,16w+16).
// Weights resident in registers as hi/lo B-fragments.
// Pipeline: child idx prefetched 2 iters ahead, gathers + cont 1 iter ahead.
template<bool LEAF, bool FINAL, int MINW>
__global__ __launch_bounds__(256, MINW)
void grnn_mfma(const float* __restrict__ cont,   // ntiles*16 x 32 (fp32)
               const int*   __restrict__ child,  // ntiles*16 x 2
               const void*  __restrict__ ein_,   // emb_{j+1} hi/lo planes or contents8 fp32
               const float* __restrict__ Wu,     // 32 x 64
               const float* __restrict__ bu,     // 64
               const float* __restrict__ Wh,     // 192 x 64
               const float* __restrict__ bh,     // 64
               void*        __restrict__ eout_,  // hi/lo planes (or fp32 if FINAL)
               int ntiles)
{
    constexpr int NP = LEAF ? 6 : 2;              // planes per buffer
    __shared__ __align__(16) char lds[NP * 2 * 2048];  // double-buffered

    const int lane = threadIdx.x & 63;
    const int w    = threadIdx.x >> 6;
    const int cidx = lane & 15;   // A-row / C-col index
    const int g    = lane >> 4;   // k-group

    // ---- weight B-fragments, hi/lo, resident in registers ----
    short8 WhH[6], WhL[6], WuH, WuL;
#pragma unroll
    for (int s = 0; s < 6; ++s) {
#pragma unroll
        for (int i = 0; i < 8; ++i) {
            unsigned short hh, ll;
            splitf(Wh[(32 * s + 8 * g + i) * 64 + 16 * w + cidx], hh, ll);
            WhH[s][i] = (short)hh; WhL[s][i] = (short)ll;
        }
    }
#pragma unroll
    for (int i = 0; i < 8; ++i) {
        unsigned short hh, ll;
        splitf(Wu[(8 * g + i) * 64 + 16 * w + cidx], hh, ll);
        WuH[i] = (short)hh; WuL[i] = (short)ll;
    }
    const float bul = bu[16 * w + cidx];
    const float bhl = bh[16 * w + cidx];

    const unsigned short* eb = (const unsigned short*)ein_;
    const float*          ef = (const float*)ein_;
    const int S = gridDim.x;
    const int t0 = blockIdx.x;

    // ---- pipeline state (1-ahead data, 2-ahead child idx) ----
    short8 gh[2][2], glo[2][2];
    f32x4  xl[2][2];
    f32x4  ca, cb;
    int2   ch_nxt;

    {   // prologue: load for t0, child idx for t0+S
        int2 c0 = *(const int2*)(child + 2 * (t0 * 16 + cidx));
        if (LEAF) {
            const f32x4* pL = (const f32x4*)(ef + (size_t)c0.x * 32 + 8 * g);
            const f32x4* pR = (const f32x4*)(ef + (size_t)c0.y * 32 + 8 * g);
            xl[0][0] = pL[0]; xl[0][1] = pL[1];
            xl[1][0] = pR[0]; xl[1][1] = pR[1];
        } else {
            const unsigned short* pL = eb + (size_t)c0.x * 128 + 8 * g;
            const unsigned short* pR = eb + (size_t)c0.y * 128 + 8 * g;
#pragma unroll
            for (int s = 0; s < 2; ++s) {
                gh [0][s] = *(const short8*)(pL + 32 * s);
                glo[0][s] = *(const short8*)(pL + 64 + 32 * s);
                gh [1][s] = *(const short8*)(pR + 32 * s);
                glo[1][s] = *(const short8*)(pR + 64 + 32 * s);
            }
        }
        const f32x4* pc = (const f32x4*)(cont + (size_t)(t0 * 16 + cidx) * 32 + 8 * g);
        ca = pc[0]; cb = pc[1];
        int t1 = (t0 + S < ntiles) ? (t0 + S) : t0;
        ch_nxt = *(const int2*)(child + 2 * (t1 * 16 + cidx));
    }

    int p = 0;
    for (int t = t0; t < ntiles; t += S, p ^= 1) {
        const int tn = (t + S < ntiles) ? (t + S) : t;   // clamped prefetch tile
        char* base = lds + p * (NP * 2048);

        f32x4 acc0 = {bhl, bhl, bhl, bhl};
        f32x4 acc1 = {0.f, 0.f, 0.f, 0.f};
        short8 AH, AL;
        const unsigned cb2 = 2u * (16 * w + cidx);

        if (!LEAF) {
            // phase1a: gather-slot MFMAs FIRST (consume prefetched gh/glo)
#pragma unroll
            for (int side = 0; side < 2; ++side) {
#pragma unroll
                for (int s = 0; s < 2; ++s) {
                    const int Sl = 2 * side + s;
                    f32x4 &acc = side ? acc1 : acc0;
                    acc = MFMA16(gh [side][s], WhH[Sl], acc);
                    acc = MFMA16(gh [side][s], WhL[Sl], acc);
                    acc = MFMA16(glo[side][s], WhH[Sl], acc);
                }
            }
            // issue next-tile gathers (covered by rest of this iteration)
            {
                const unsigned short* pL = eb + (size_t)ch_nxt.x * 128 + 8 * g;
                const unsigned short* pR = eb + (size_t)ch_nxt.y * 128 + 8 * g;
#pragma unroll
                for (int s = 0; s < 2; ++s) {
                    gh [0][s] = *(const short8*)(pL + 32 * s);
                    glo[0][s] = *(const short8*)(pL + 64 + 32 * s);
                    gh [1][s] = *(const short8*)(pR + 32 * s);
                    glo[1][s] = *(const short8*)(pR + 64 + 32 * s);
                }
            }
            {
                int t2 = (t + 2 * S < ntiles) ? (t + 2 * S) : tn;
                ch_nxt = *(const int2*)(child + 2 * (t2 * 16 + cidx));
            }
            // phase1b: u = relu(cont @ Wu + bu), split, stash
            split8(ca, cb, AH, AL);
            f32x4 ua = {bul, bul, bul, bul};
            ua = MFMA16(AH, WuH, ua);
            ua = MFMA16(AH, WuL, ua);
            ua = MFMA16(AL, WuH, ua);
            {   // issue next-tile cont
                const f32x4* pc = (const f32x4*)(cont + (size_t)(tn * 16 + cidx) * 32 + 8 * g);
                ca = pc[0]; cb = pc[1];
            }
#pragma unroll
            for (int i = 0; i < 4; ++i) {
                unsigned short hh, ll;
                splitf(fmaxf(ua[i], 0.f), hh, ll);
                *(unsigned short*)(base + 0 * 2048 + swz(4 * g + i, cb2)) = hh;
                *(unsigned short*)(base + 1 * 2048 + swz(4 * g + i, cb2)) = ll;
            }
        } else {
            // leaf phase1: u, uL, uR (consume prefetched cont + xl)
            split8(ca, cb, AH, AL);
            f32x4 ua = {bul, bul, bul, bul};
            ua = MFMA16(AH, WuH, ua);
            ua = MFMA16(AH, WuL, ua);
            ua = MFMA16(AL, WuH, ua);
            split8(xl[0][0], xl[0][1], AH, AL);
            f32x4 uLa = {bul, bul, bul, bul};
            uLa = MFMA16(AH, WuH, uLa);
            uLa = MFMA16(AH, WuL, uLa);
            uLa = MFMA16(AL, WuH, uLa);
            split8(xl[1][0], xl[1][1], AH, AL);
            f32x4 uRa = {bul, bul, bul, bul};
            uRa = MFMA16(AH, WuH, uRa);
            uRa = MFMA16(AH, WuL, uRa);
            uRa = MFMA16(AL, WuH, uRa);
            {   // issue next-tile gathers + cont
                const f32x4* pL = (const f32x4*)(ef + (size_t)ch_nxt.x * 32 + 8 * g);
                const f32x4* pR = (const f32x4*)(ef + (size_t)ch_nxt.y * 32 + 8 * g);
                xl[0][0] = pL[0]; xl[0][1] = pL[1];
                xl[1][0] = pR[0]; xl[1][1] = pR[1];
            }
            {
                int t2 = (t + 2 * S < ntiles) ? (t + 2 * S) : tn;
                ch_nxt = *(const int2*)(child + 2 * (t2 * 16 + cidx));
            }
            {
                const f32x4* pc = (const f32x4*)(cont + (size_t)(tn * 16 + cidx) * 32 + 8 * g);
                ca = pc[0]; cb = pc[1];
            }
#pragma unroll
            for (int i = 0; i < 4; ++i) {
                const unsigned row = 4 * g + i;
                unsigned short hh, ll;
                splitf(fmaxf(uLa[i], 0.f), hh, ll);
                *(unsigned short*)(base + 0 * 2048 + swz(row, cb2)) = hh;
                *(unsigned short*)(base + 1 * 2048 + swz(row, cb2)) = ll;
                splitf(fmaxf(uRa[i], 0.f), hh, ll);
                *(unsigned short*)(base + 2 * 2048 + swz(row, cb2)) = hh;
                *(unsigned short*)(base + 3 * 2048 + swz(row, cb2)) = ll;
                splitf(fmaxf(ua[i], 0.f), hh, ll);
                *(unsigned short*)(base + 4 * 2048 + swz(row, cb2)) = hh;
                *(unsigned short*)(base + 5 * 2048 + swz(row, cb2)) = ll;
            }
        }

        barrier_nv();   // LDS-visibility barrier; prefetches stay in flight

        // phase2: remaining slots from LDS
        if (LEAF) {
#pragma unroll
            for (int q = 0; q < 3; ++q) {
#pragma unroll
                for (int s = 0; s < 2; ++s) {
                    const short8 aH = *(const short8*)(base + (2 * q + 0) * 2048 + swz(cidx, 64 * s + 16 * g));
                    const short8 aL = *(const short8*)(base + (2 * q + 1) * 2048 + swz(cidx, 64 * s + 16 * g));
                    const int Sl = 2 * q + s;
                    f32x4 &acc = s ? acc1 : acc0;
                    acc = MFMA16(aH, WhH[Sl], acc);
                    acc = MFMA16(aH, WhL[Sl], acc);
                    acc = MFMA16(aL, WhH[Sl], acc);
                }
            }
        } else {
#pragma unroll
            for (int s = 0; s < 2; ++s) {
                const short8 aH = *(const short8*)(base + 0 * 2048 + swz(cidx, 64 * s + 16 * g));
                const short8 aL = *(const short8*)(base + 1 * 2048 + swz(cidx, 64 * s + 16 * g));
                const int Sl = 4 + s;
                f32x4 &acc = s ? acc1 : acc0;
                acc = MFMA16(aH, WhH[Sl], acc);
                acc = MFMA16(aH, WhL[Sl], acc);
                acc = MFMA16(aL, WhH[Sl], acc);
            }
        }

        // store
        if (FINAL) {
            float* out = (float*)eout_;
#pragma unroll
            for (int i = 0; i < 4; ++i)
                out[(size_t)(t * 16 + 4 * g + i) * 64 + 16 * w + cidx] = fmaxf(acc0[i] + acc1[i], 0.f);
        } else {
            unsigned short* out = (unsigned short*)eout_;
#pragma unroll
            for (int i = 0; i < 4; ++i) {
                unsigned short hh, ll;
                splitf(fmaxf(acc0[i] + acc1[i], 0.f), hh, ll);
                const size_t rb = (size_t)(t * 16 + 4 * g + i) * 128;
                out[rb + 16 * w + cidx]      = hh;
                out[rb + 64 + 16 * w + cidx] = ll;
            }
        }
    }
}

extern "C" void kernel_launch(void* const* d_in, const int* in_sizes, int n_in,
                              void* d_out, int out_size, void* d_ws, size_t ws_size,
                              hipStream_t stream) {
    // inputs: contents0..8 = d_in[0..8], children0..7 = d_in[9..16],
    //         Wu = d_in[17], bu = d_in[18], Wh = d_in[19], bh = d_in[20]
    const float* Wu = (const float*)d_in[17];
    const float* bu = (const float*)d_in[18];
    const float* Wh = (const float*)d_in[19];
    const float* bh = (const float*)d_in[20];

    // emb_j stored as bf16 hi/lo planes, 256B/row -> same footprint as fp32
    void* bufA = d_ws;                               // emb7/5/3/1 (max 256 MiB)
    void* bufB = (char*)d_ws + (size_t)268435456;    // emb6/4/2

    const void* ein = d_in[8];  // contents8 (fp32) for the fused leaf level
    for (int j = 7; j >= 0; --j) {
        const int n      = in_sizes[j] / 32;
        const int ntiles = n / 16;
        void* eout = (j == 0) ? d_out : ((j & 1) ? bufA : bufB);
        int blocks = ntiles < 4096 ? ntiles : 4096;
        const float* cont  = (const float*)d_in[j];
        const int*   child = (const int*)d_in[9 + j];
        if (j == 7)
            grnn_mfma<true,  false, 4><<<blocks, 256, 0, stream>>>(cont, child, ein, Wu, bu, Wh, bh, eout, ntiles);
        else if (j == 0)
            grnn_mfma<false, true,  3><<<blocks, 256, 0, stream>>>(cont, child, ein, Wu, bu, Wh, bh, eout, ntiles);
        else
            grnn_mfma<false, false, 3><<<blocks, 256, 0, stream>>>(cont, child, ein, Wu, bu, Wh, bh, eout, ntiles);
        ein = eout;
    }
}

// Round 6
// 709.420 us; speedup vs baseline: 1.1077x; 1.1077x over previous
//
#include <hip/hip_runtime.h>
#include <hip/hip_bf16.h>

typedef __attribute__((ext_vector_type(8))) short  short8;
typedef __attribute__((ext_vector_type(4))) float  f32x4;

#define MFMA16(A,B,C) __builtin_amdgcn_mfma_f32_16x16x32_bf16((A),(B),(C),0,0,0)

// ---- fp32 -> bf16 hi/lo split, pair-packed via cvt_pk (compiler-lowered) ----
// hi = bf16_rne(x); lo = bf16_rne(x - hi). Residual ~2^-17 |x|.
// hp = [bf16(x1) : bf16(x0)] packed dword; lp likewise for the residuals.
__device__ __forceinline__ void split2(float x0, float x1, unsigned &hp, unsigned &lp) {
    __hip_bfloat162 h = __float22bfloat162_rn(float2{x0, x1});
    union { __hip_bfloat162 b; unsigned u; } uh, ul;
    uh.b = h;
    float f0 = __bfloat162float(h.x);
    float f1 = __bfloat162float(h.y);
    ul.b = __float22bfloat162_rn(float2{x0 - f0, x1 - f1});
    hp = uh.u;
    lp = ul.u;
}

__device__ __forceinline__ void split8(const f32x4 a, const f32x4 b, short8 &h, short8 &l) {
    union { short8 s; unsigned u[4]; } H, L;
    split2(a[0], a[1], H.u[0], L.u[0]);
    split2(a[2], a[3], H.u[1], L.u[1]);
    split2(b[0], b[1], H.u[2], L.u[2]);
    split2(b[2], b[3], H.u[3], L.u[3]);
    h = H.s; l = L.s;
}

// XOR-swizzled byte offset inside a [16 rows][64 bf16] plane (row stride 128B).
__device__ __forceinline__ unsigned swz(unsigned row, unsigned colbyte) {
    return row * 128u + (colbyte ^ ((row & 7u) << 4));
}

// One tree level. Block = 4 waves; wave w owns output cols [16w,16w+16).
// Weights resident in registers as hi/lo B-fragments.
// LEAF:  children gather contents8 (fp32, 32-wide); u8 recomputed on the fly.
// !LEAF: children gather emb_{j+1} stored as bf16 hi/lo planes (256B/row) ->
//        fragments feed MFMA directly, no split.
// FINAL: fp32 output to d_out; else hi/lo planes.
template<bool LEAF, bool FINAL, int MINW>
__global__ __launch_bounds__(256, MINW)
void grnn_mfma(const float* __restrict__ cont,   // ntiles*16 x 32 (fp32)
               const int*   __restrict__ child,  // ntiles*16 x 2
               const void*  __restrict__ ein_,   // emb_{j+1} hi/lo planes or contents8 fp32
               const float* __restrict__ Wu,     // 32 x 64
               const float* __restrict__ bu,     // 64
               const float* __restrict__ Wh,     // 192 x 64
               const float* __restrict__ bh,     // 64
               void*        __restrict__ eout_,  // hi/lo planes (or fp32 if FINAL)
               int ntiles)
{
    constexpr int NP = LEAF ? 6 : 2;              // planes (single-buffered)
    __shared__ __align__(16) char lds[NP * 2048];

    const int lane = threadIdx.x & 63;
    const int w    = threadIdx.x >> 6;
    const int cidx = lane & 15;   // A-row / C-col index
    const int g    = lane >> 4;   // k-group

    // ---- weight B-fragments, hi/lo, resident in registers ----
    short8 WhH[6], WhL[6], WuH, WuL;
#pragma unroll
    for (int s = 0; s < 6; ++s) {
        union { short8 s8; unsigned u[4]; } H, L;
#pragma unroll
        for (int q = 0; q < 4; ++q) {
            const int k = 32 * s + 8 * g + 2 * q;
            split2(Wh[k * 64 + 16 * w + cidx], Wh[(k + 1) * 64 + 16 * w + cidx], H.u[q], L.u[q]);
        }
        WhH[s] = H.s8; WhL[s] = L.s8;
    }
    {
        union { short8 s8; unsigned u[4]; } H, L;
#pragma unroll
        for (int q = 0; q < 4; ++q) {
            const int k = 8 * g + 2 * q;
            split2(Wu[k * 64 + 16 * w + cidx], Wu[(k + 1) * 64 + 16 * w + cidx], H.u[q], L.u[q]);
        }
        WuH = H.s8; WuL = L.s8;
    }
    const float bul = bu[16 * w + cidx];
    const float bhl = bh[16 * w + cidx];

    const unsigned short* eb = (const unsigned short*)ein_;
    const float*          ef = (const float*)ein_;

    for (int t = blockIdx.x; t < ntiles; t += gridDim.x) {
        const int r = t * 16 + cidx;
        const int2 ch = *(const int2*)(child + 2 * r);

        // ---- issue gathers first (consumed after phase 1) ----
        short8 gh[2][2], glo[2][2];   // !LEAF: [side][kstep] hi/lo fragments
        f32x4  xl[2][2];              // LEAF:  [side][half] contents8 fp32
        if (LEAF) {
            const f32x4* pL = (const f32x4*)(ef + (size_t)ch.x * 32 + 8 * g);
            const f32x4* pR = (const f32x4*)(ef + (size_t)ch.y * 32 + 8 * g);
            xl[0][0] = pL[0]; xl[0][1] = pL[1];
            xl[1][0] = pR[0]; xl[1][1] = pR[1];
        } else {
            const unsigned short* pL = eb + (size_t)ch.x * 128 + 8 * g;
            const unsigned short* pR = eb + (size_t)ch.y * 128 + 8 * g;
#pragma unroll
            for (int s = 0; s < 2; ++s) {
                gh [0][s] = *(const short8*)(pL + 32 * s);
                glo[0][s] = *(const short8*)(pL + 64 + 32 * s);
                gh [1][s] = *(const short8*)(pR + 32 * s);
                glo[1][s] = *(const short8*)(pR + 64 + 32 * s);
            }
        }
        const f32x4* pc = (const f32x4*)(cont + (size_t)r * 32 + 8 * g);
        const f32x4 ca = pc[0], cbv = pc[1];

        // ---- phase 1: u tiles (K=32), relu, split, stash in LDS ----
        short8 AH, AL;
        split8(ca, cbv, AH, AL);
        f32x4 ua = {bul, bul, bul, bul};
        ua = MFMA16(AH, WuH, ua);
        ua = MFMA16(AH, WuL, ua);
        ua = MFMA16(AL, WuH, ua);

        f32x4 uLa, uRa;
        if (LEAF) {
            split8(xl[0][0], xl[0][1], AH, AL);
            uLa = {bul, bul, bul, bul};
            uLa = MFMA16(AH, WuH, uLa);
            uLa = MFMA16(AH, WuL, uLa);
            uLa = MFMA16(AL, WuH, uLa);
            split8(xl[1][0], xl[1][1], AH, AL);
            uRa = {bul, bul, bul, bul};
            uRa = MFMA16(AH, WuH, uRa);
            uRa = MFMA16(AH, WuL, uRa);
            uRa = MFMA16(AL, WuH, uRa);
        }

        const unsigned cb2 = 2u * (16 * w + cidx);
#pragma unroll
        for (int i = 0; i < 4; i += 2) {
            const unsigned r0 = swz(4 * g + i, cb2), r1 = swz(4 * g + i + 1, cb2);
            unsigned hp, lp;
            split2(fmaxf(ua[i], 0.f), fmaxf(ua[i + 1], 0.f), hp, lp);
            *(unsigned short*)(lds + (NP - 2) * 2048 + r0) = (unsigned short)hp;
            *(unsigned short*)(lds + (NP - 2) * 2048 + r1) = (unsigned short)(hp >> 16);
            *(unsigned short*)(lds + (NP - 1) * 2048 + r0) = (unsigned short)lp;
            *(unsigned short*)(lds + (NP - 1) * 2048 + r1) = (unsigned short)(lp >> 16);
            if (LEAF) {
                split2(fmaxf(uLa[i], 0.f), fmaxf(uLa[i + 1], 0.f), hp, lp);
                *(unsigned short*)(lds + 0 * 2048 + r0) = (unsigned short)hp;
                *(unsigned short*)(lds + 0 * 2048 + r1) = (unsigned short)(hp >> 16);
                *(unsigned short*)(lds + 1 * 2048 + r0) = (unsigned short)lp;
                *(unsigned short*)(lds + 1 * 2048 + r1) = (unsigned short)(lp >> 16);
                split2(fmaxf(uRa[i], 0.f), fmaxf(uRa[i + 1], 0.f), hp, lp);
                *(unsigned short*)(lds + 2 * 2048 + r0) = (unsigned short)hp;
                *(unsigned short*)(lds + 2 * 2048 + r1) = (unsigned short)(hp >> 16);
                *(unsigned short*)(lds + 3 * 2048 + r0) = (unsigned short)lp;
                *(unsigned short*)(lds + 3 * 2048 + r1) = (unsigned short)(lp >> 16);
            }
        }
        __syncthreads();

        // ---- phase 2: emb = relu([hL|hR|u] @ Wh + bh) ----
        f32x4 acc0 = {bhl, bhl, bhl, bhl};
        f32x4 acc1 = {0.f, 0.f, 0.f, 0.f};
        if (LEAF) {
#pragma unroll
            for (int q = 0; q < 3; ++q) {
#pragma unroll
                for (int s = 0; s < 2; ++s) {
                    const short8 aH = *(const short8*)(lds + (2 * q + 0) * 2048 + swz(cidx, 64 * s + 16 * g));
                    const short8 aL = *(const short8*)(lds + (2 * q + 1) * 2048 + swz(cidx, 64 * s + 16 * g));
                    const int S = 2 * q + s;
                    f32x4 &acc = s ? acc1 : acc0;
                    acc = MFMA16(aH, WhH[S], acc);
                    acc = MFMA16(aH, WhL[S], acc);
                    acc = MFMA16(aL, WhH[S], acc);
                }
            }
        } else {
#pragma unroll
            for (int side = 0; side < 2; ++side) {
#pragma unroll
                for (int s = 0; s < 2; ++s) {
                    const int S = 2 * side + s;
                    f32x4 &acc = side ? acc1 : acc0;
                    acc = MFMA16(gh [side][s], WhH[S], acc);
                    acc = MFMA16(gh [side][s], WhL[S], acc);
                    acc = MFMA16(glo[side][s], WhH[S], acc);
                }
            }
#pragma unroll
            for (int s = 0; s < 2; ++s) {
                const short8 aH = *(const short8*)(lds + 0 * 2048 + swz(cidx, 64 * s + 16 * g));
                const short8 aL = *(const short8*)(lds + 1 * 2048 + swz(cidx, 64 * s + 16 * g));
                const int S = 4 + s;
                f32x4 &acc = s ? acc1 : acc0;
                acc = MFMA16(aH, WhH[S], acc);
                acc = MFMA16(aH, WhL[S], acc);
                acc = MFMA16(aL, WhH[S], acc);
            }
        }

        // ---- store ----
        if (FINAL) {
            float* out = (float*)eout_;
#pragma unroll
            for (int i = 0; i < 4; ++i)
                out[(size_t)(t * 16 + 4 * g + i) * 64 + 16 * w + cidx] = fmaxf(acc0[i] + acc1[i], 0.f);
        } else {
            unsigned short* out = (unsigned short*)eout_;
            const unsigned c = 16 * w + cidx;
#pragma unroll
            for (int i = 0; i < 4; i += 2) {
                unsigned hp, lp;
                split2(fmaxf(acc0[i] + acc1[i], 0.f), fmaxf(acc0[i + 1] + acc1[i + 1], 0.f), hp, lp);
                const size_t rb0 = (size_t)(t * 16 + 4 * g + i) * 128;
                const size_t rb1 = rb0 + 128;
                out[rb0 + c]      = (unsigned short)hp;
                out[rb1 + c]      = (unsigned short)(hp >> 16);
                out[rb0 + 64 + c] = (unsigned short)lp;
                out[rb1 + 64 + c] = (unsigned short)(lp >> 16);
            }
        }
        __syncthreads();
    }
}

extern "C" void kernel_launch(void* const* d_in, const int* in_sizes, int n_in,
                              void* d_out, int out_size, void* d_ws, size_t ws_size,
                              hipStream_t stream) {
    // inputs: contents0..8 = d_in[0..8], children0..7 = d_in[9..16],
    //         Wu = d_in[17], bu = d_in[18], Wh = d_in[19], bh = d_in[20]
    const float* Wu = (const float*)d_in[17];
    const float* bu = (const float*)d_in[18];
    const float* Wh = (const float*)d_in[19];
    const float* bh = (const float*)d_in[20];

    // emb_j stored as bf16 hi/lo planes, 256B/row -> same footprint as fp32
    void* bufA = d_ws;                               // emb7/5/3/1 (max 256 MiB)
    void* bufB = (char*)d_ws + (size_t)268435456;    // emb6/4/2

    const void* ein = d_in[8];  // contents8 (fp32) for the fused leaf level
    for (int j = 7; j >= 0; --j) {
        const int n      = in_sizes[j] / 32;
        const int ntiles = n / 16;
        void* eout = (j == 0) ? d_out : ((j & 1) ? bufA : bufB);
        int blocks = ntiles < 4096 ? ntiles : 4096;
        const float* cont  = (const float*)d_in[j];
        const int*   child = (const int*)d_in[9 + j];
        if (j == 7)
            grnn_mfma<true,  false, 4><<<blocks, 256, 0, stream>>>(cont, child, ein, Wu, bu, Wh, bh, eout, ntiles);
        else if (j == 0)
            grnn_mfma<false, true,  3><<<blocks, 256, 0, stream>>>(cont, child, ein, Wu, bu, Wh, bh, eout, ntiles);
        else
            grnn_mfma<false, false, 3><<<blocks, 256, 0, stream>>>(cont, child, ein, Wu, bu, Wh, bh, eout, ntiles);
        ein = eout;
    }
}